// Round 16
// baseline (91.763 us; speedup 1.0000x reference)
//
#include <hip/hip_runtime.h>
#include <hip/hip_bf16.h>
#include <math.h>

#define NEGC -1000000000.0f

using f32x2 = __attribute__((ext_vector_type(2))) float;
using f32x4 = __attribute__((ext_vector_type(4))) float;
using s16x8 = __attribute__((ext_vector_type(8))) short;

__device__ __forceinline__ float softplusf(float v){ return log1pf(expf(v)); }
__device__ __forceinline__ float frcp(float v){ return __builtin_amdgcn_rcpf(v); }
__device__ __forceinline__ short bfs(float f){      // compiler emits v_cvt_pk_bf16_f32 pairs
  __hip_bfloat16 h = __float2bfloat16(f);
  short s; __builtin_memcpy(&s, &h, 2); return s;
}

// ---- cross-lane adds fully OFF the DS pipe (VALU permlane/DPP); semantics HW-verified r9/r13 ----
__device__ __forceinline__ float addx32(float v){   // valid lanes 0-31
#if __has_builtin(__builtin_amdgcn_permlane32_swap)
  auto r = __builtin_amdgcn_permlane32_swap(__float_as_uint(v), __float_as_uint(v), false, false);
  return v + __uint_as_float(r[1]);
#else
  return v + __shfl_xor(v, 32, 64);
#endif
}
__device__ __forceinline__ float addx16(float v){   // valid lanes 0-15
#if __has_builtin(__builtin_amdgcn_permlane16_swap)
  auto r = __builtin_amdgcn_permlane16_swap(__float_as_uint(v), __float_as_uint(v), false, false);
  return v + __uint_as_float(r[1]);
#else
  return v + __shfl_xor(v, 16, 64);
#endif
}
__device__ __forceinline__ float addx8(float v){    // xor8 via DPP row_ror:8
  int s = __builtin_amdgcn_update_dpp(0, __float_as_int(v), 0x128, 0xF, 0xF, true);
  return v + __int_as_float(s);
}
__device__ __forceinline__ float addq1(float v){    // xor1 via quad_perm
  int s = __builtin_amdgcn_update_dpp(0, __float_as_int(v), 0xB1, 0xF, 0xF, true);
  return v + __int_as_float(s);
}
__device__ __forceinline__ float addq2(float v){    // xor2 via quad_perm
  int s = __builtin_amdgcn_update_dpp(0, __float_as_int(v), 0x4E, 0xF, 0xF, true);
  return v + __int_as_float(s);
}
// ^7 ROW_HALF_MIRROR: equals ^4-add when input is quad-uniform (after addq1+addq2)
__device__ __forceinline__ float addrhm(float v){
  int s = __builtin_amdgcn_update_dpp(0, __float_as_int(v), 0x141, 0xF, 0xF, true);
  return v + __int_as_float(s);
}
// ^15 ROW_MIRROR: equals ^8-add when input is 8-group-uniform
__device__ __forceinline__ float addrm(float v){
  int s = __builtin_amdgcn_update_dpp(0, __float_as_int(v), 0x140, 0xF, 0xF, true);
  return v + __int_as_float(s);
}

// ---------------- Kernel A: W1-pack (blocks 0-15) + scan-based classification (block 16) --------
__global__ __launch_bounds__(256) void k_prep(const float* __restrict__ W1,
                                              short* __restrict__ wpack,
                                              const int* __restrict__ batch,
                                              int* __restrict__ starts, int T, int Bn,
                                              int* __restrict__ cnt,
                                              int* __restrict__ bigs,
                                              int* __restrict__ smalls){
  const int bx  = blockIdx.x;
  const int tid = threadIdx.x;
  if (bx < 16){
    int gid  = bx * 256 + tid;                 // 0..4095
    int lane = gid & 63;
    int ft   = gid >> 6;
    int kt   = ft >> 2;
    int dt   = ft & 3;
    const float* src = W1 + (size_t)(kt * 16 + (lane & 15)) * 128 + dt * 32 + (lane >> 4) * 8;
    short o[8];
#pragma unroll
    for (int e = 0; e < 8; ++e) o[e] = bfs(src[e]);
    *(s16x8*)(wpack + (size_t)gid * 8) = *(const s16x8*)o;
    return;
  }
  // block 16: all starts via interleaved binary searches, then prefix-scan classification
  __shared__ int sstart[2049];      // supports Bn <= 2048 (problem: Bn = 1024)
  __shared__ int scn[256];
  int lo[8], hi[8];
  int ns = 0;
  for (int t = tid; t <= Bn; t += 256){ if (ns < 8){ lo[ns] = 0; hi[ns] = T; } ns++; }
  if (ns > 8) ns = 8;
  for (int step = 0; step < 24; ++step){     // covers T < 16M; idle once converged
#pragma unroll
    for (int q = 0; q < 8; ++q){
      if (q < ns && lo[q] < hi[q]){
        int t   = tid + (q << 8);
        int mid = (lo[q] + hi[q]) >> 1;
        if (batch[mid] < t) lo[q] = mid + 1; else hi[q] = mid;
      }
    }
  }
#pragma unroll
  for (int q = 0; q < 8; ++q) if (q < ns){
    int t = tid + (q << 8);
    starts[t] = lo[q];
    if (t <= 2048) sstart[t] = lo[q];
  }
  __syncthreads();
  const int ck = (Bn + 255) >> 8;            // segments per thread (contiguous)
  const int s0 = tid * ck;
  int myb = 0; unsigned flags = 0;
#pragma unroll
  for (int q = 0; q < 8; ++q){
    int s = s0 + q;
    if (q < ck && s < Bn){
      int nb = sstart[s + 1] - sstart[s];
      if (nb > 64){ flags |= (1u << q); myb++; }
    }
  }
  scn[tid] = myb;
  __syncthreads();
  for (int off = 1; off < 256; off <<= 1){
    int v = scn[tid];
    int w = (tid >= off) ? scn[tid - off] : 0;
    __syncthreads();
    scn[tid] = v + w;
    __syncthreads();
  }
  int bposs = scn[tid] - myb;                // bigs strictly before s0
  if (tid == 255){ cnt[0] = scn[255]; cnt[1] = Bn - scn[255]; }
#pragma unroll
  for (int q = 0; q < 8; ++q){
    int s = s0 + q;
    if (q < ck && s < Bn){
      if (flags & (1u << q)){ bigs[bposs] = s; bposs++; }
      else                  { smalls[s - bposs] = s; }
    }
  }
}

// ---------------- Kernel B: fused scores-MFMA + softmax + UOT-badmm (one item/block) ----------------
__global__ __launch_bounds__(1024)
void k_uot(const float* __restrict__ x,
           const int*   __restrict__ starts,
           const int*   __restrict__ cnt,
           const int*   __restrict__ bigs,
           const int*   __restrict__ smalls,
           const short* __restrict__ wpack,
           const float* __restrict__ W2,
           const float* __restrict__ a1r,
           const float* __restrict__ a2r,
           const float* __restrict__ a3r,
           float* __restrict__ out, int T){
  __shared__ __align__(16) short xs[2 * 64 * 128];      // 32 KB
  __shared__ __align__(16) float pbuf[16][164];
  __shared__ float scpart[2][4][64];
  __shared__ float rcsb[2][128];
  __shared__ float lq0s[2][128];
  __shared__ float sred[2][2];

  const int b   = blockIdx.x;
  const int tid = threadIdx.x;
  const int nbig   = cnt[0];
  const int nsmall = cnt[1];

  bool solo; int seg;
  const int half  = tid >> 9;
  const int tid_l = tid & 511;
  if (b < nbig){
    solo = true; seg = bigs[b];
  } else {
    const int i = (b - nbig) * 2 + half;
    solo = false;
    if ((b - nbig) * 2 >= nsmall) return;          // ghost block (uniform) -> no barrier reached
    if (i >= nsmall) return;                       // half B missing -> waves exit
    seg = smalls[i];
  }

  const int start = starts[seg];
  const int nbr   = starts[seg + 1] - start;
  const int hh    = solo ? 0 : half;
  const int tl    = solo ? tid : tid_l;
  const int PL    = solo ? 8 : 4;

  if (nbr <= 0){
    if (tl < 128) out[(size_t)seg * 128 + tl] = 0.f;
    return;
  }

  const int n    = tl >> 3;
  const int j    = tl & 7;
  const int wvi  = tid >> 6;
  const int lane = tid & 63;
  const int part = tl & (PL - 1);
  const int col  = tl / PL;
  const int cidx = (col >> 4) * 20 + (col & 15);
  const int wq0  = solo ? 0 : half * 8;

  // ===== Phase 1: stage unit rows as swizzled bf16 =====
  const int u      = tid >> 9;
  const int ustart = solo ? (start + u * 64) : start;
#pragma unroll
  for (int itr = 0; itr < 2; ++itr){
    int L  = (itr * 512 + tid_l) * 8;
    int rr = L >> 7;
    int dc = L & 127;
    int grow = ustart + rr; grow = (grow < T) ? grow : (T - 1);
    const float4 v0 = *(const float4*)(x + (size_t)grow * 128 + dc);
    const float4 v1 = *(const float4*)(x + (size_t)grow * 128 + dc + 4);
    short o[8] = {bfs(v0.x), bfs(v0.y), bfs(v0.z), bfs(v0.w),
                  bfs(v1.x), bfs(v1.y), bfs(v1.z), bfs(v1.w)};
    int byte = u * 16384 + rr * 256 + ((dc * 2) ^ ((rr & 7) << 4));
    *(s16x8*)((char*)xs + byte) = *(const s16x8*)o;
  }
  __syncthreads();

  // ===== Phase 2: scores MFMA + tanh*W2 epilogue =====
  {
    const int lw = wvi & 7;
    const int wm = lw & 1;
    const int wn = lw >> 1;
    f32x4 acc[2][4];
#pragma unroll
    for (int mt = 0; mt < 2; ++mt)
#pragma unroll
      for (int kt = 0; kt < 4; ++kt) acc[mt][kt] = (f32x4){0.f, 0.f, 0.f, 0.f};

    const s16x8* wp = (const s16x8*)wpack;
#pragma unroll
    for (int dt = 0; dt < 4; ++dt){
      s16x8 av[2];
#pragma unroll
      for (int mt = 0; mt < 2; ++mt){
        int arow = wm * 32 + mt * 16 + (lane & 15);
        int byte = u * 16384 + arow * 256 + ((dt * 64 + (lane >> 4) * 16) ^ ((arow & 7) << 4));
        av[mt] = *(const s16x8*)((const char*)xs + byte);
      }
#pragma unroll
      for (int kt = 0; kt < 4; ++kt){
        s16x8 wv = wp[(size_t)((((wn * 4 + kt) * 4 + dt)) << 6) + lane];
#pragma unroll
        for (int mt = 0; mt < 2; ++mt)
          acc[mt][kt] = __builtin_amdgcn_mfma_f32_16x16x32_bf16(av[mt], wv, acc[mt][kt], 0, 0, 0);
      }
    }

    float psum[2][4] = {{0.f,0.f,0.f,0.f},{0.f,0.f,0.f,0.f}};
#pragma unroll
    for (int kt = 0; kt < 4; ++kt){
      const float w2v  = W2[(wn * 4 + kt) * 16 + (lane & 15)];
      const float w2v2 = w2v + w2v;
#pragma unroll
      for (int mt = 0; mt < 2; ++mt)
#pragma unroll
        for (int r = 0; r < 4; ++r){
          float e = __expf(2.f * acc[mt][kt][r]);
          psum[mt][r] = fmaf(-w2v2, frcp(e + 1.f), psum[mt][r] + w2v);   // += tanh*w2
        }
    }
#pragma unroll
    for (int mt = 0; mt < 2; ++mt)
#pragma unroll
      for (int r = 0; r < 4; ++r){
        float v = psum[mt][r];
        v = addq1(v); v = addq2(v);
        v = addrhm(v);                 // ^4 (quad-uniform)
        v = addrm(v);                  // ^8 (8-uniform)
        if ((lane & 15) == 0)
          scpart[u][wn][wm * 32 + mt * 16 + (lane >> 4) * 4 + r] = v;
      }
  }
  __syncthreads();

  // ===== Phase 3': merged score-combine + softmax stats (one barrier) =====
  float sc = NEGC;
  if (tl < 128 && tl < nbr){
    const int ru = solo ? (tl >> 6) : hh;
    const int rl = tl & 63;
    sc = scpart[ru][0][rl] + scpart[ru][1][rl] + scpart[ru][2][rl] + scpart[ru][3][rl];
  }
  if (tl < 128) lq0s[hh][tl] = sc;
  if ((wvi & 7) == 0 && (!solo || wvi == 0)){
    float v1 = NEGC;
    const int r2 = lane + 64;
    if (r2 < nbr){                               // only possible for solo
      const int rl2 = r2 & 63;
      v1 = scpart[1][0][rl2] + scpart[1][1][rl2] + scpart[1][2][rl2] + scpart[1][3][rl2];
    }
    float m = fmaxf(sc, v1);
#pragma unroll
    for (int msk = 32; msk; msk >>= 1) m = fmaxf(m, __shfl_xor(m, msk, 64));
    float s = __expf(sc - m) + __expf(v1 - m);
#pragma unroll
    for (int msk = 32; msk; msk >>= 1) s += __shfl_xor(s, msk, 64);
    if (lane == 0){ sred[hh][0] = m; sred[hh][1] = s; }
  }
  __syncthreads();
  const float smax  = sred[hh][0];
  const float rden  = frcp(sred[hh][1] + 1e-16f);
  const bool  valid = (n < nbr);
  const float lq0   = valid ? __logf(__expf(lq0s[hh][n] - smax) * rden + 1e-8f) : NEGC;

  // ===== Phase 4: scalars + per-row eta recursion =====
  const float a1 = softplusf(a1r[0]);
  const float a2 = softplusf(a2r[0]);
  const float a3 = softplusf(a3r[0]);
  const float inv_a1 = 1.f / a1;
  const float log_p0 = logf(1.0f / 128.0f + 1e-8f);

  float emu_use[3];
  {
    float z1 = 0.f, lp = log_p0;
    emu_use[0] = __expf(log_p0);
#pragma unroll
    for (int i = 1; i < 3; ++i){
      float nm = (a1 * lp + a2 * log_p0 - z1) / (a1 + a2);
      z1 += a1 * (__expf(nm) - __expf(lp));
      emu_use[i] = __expf(nm); lp = nm;
    }
  }
  float eeta_use[4];
  {
    float z2 = 0.f, lp = lq0;
    eeta_use[0] = __expf(lq0);
#pragma unroll
    for (int i = 1; i < 4; ++i){
      float nm = (a1 * lp + a3 * lq0 - z2) / (a1 + a3);
      z2 += a1 * (__expf(nm) - __expf(lp));
      eeta_use[i] = __expf(nm); lp = nm;
    }
  }

  const int  nc   = valid ? n : (nbr - 1);
  const float* xp = x + (size_t)(start + nc) * 128 + j * 16;    // always in-bounds
  f32x2 EX2[8], PZ2[8], S2[8];
  {
    const float s0 = __expf(lq0 + log_p0);       // exactly 0 for invalid rows
#pragma unroll
    for (int p = 0; p < 8; p += 2){
      float4 v = *(const float4*)(xp + p * 2);
      EX2[p]   = (f32x2){__expf(v.x * inv_a1), __expf(v.y * inv_a1)};
      EX2[p+1] = (f32x2){__expf(v.z * inv_a1), __expf(v.w * inv_a1)};
    }
#pragma unroll
    for (int p = 0; p < 8; ++p){ PZ2[p] = (f32x2){1.f, 1.f}; S2[p] = (f32x2){s0, s0}; }
  }

#pragma unroll
  for (int it = 0; it < 4; ++it){
    f32x2 ES2[8];
    f32x2 rs2 = (f32x2){0.f, 0.f};
#pragma unroll
    for (int p = 0; p < 8; ++p){
      ES2[p] = EX2[p] * S2[p];
      rs2 += ES2[p] * PZ2[p];
    }
    float rsum = rs2[0] + rs2[1];
    rsum = addq1(rsum);
    rsum = addq2(rsum);
    rsum = addrhm(rsum);               // ^4 (quad-uniform)
    const float Et = valid ? (eeta_use[it] * frcp(rsum)) : 0.f;
    const f32x2 Et2 = (f32x2){Et, Et};

    if (it == 3){
      float c[16];
#pragma unroll
      for (int p = 0; p < 8; p += 2){
        float4 v = *(const float4*)(xp + p * 2);
        f32x2 t0 = ES2[p]   * PZ2[p]   * Et2;
        f32x2 t1 = ES2[p+1] * PZ2[p+1] * Et2;
        c[p*2+0] = v.x * t0[0]; c[p*2+1] = v.y * t0[1];
        c[p*2+2] = v.z * t1[0]; c[p*2+3] = v.w * t1[1];
      }
#pragma unroll
      for (int k = 0; k < 16; ++k)
        c[k] = addx8(addx16(addx32(c[k])));        // valid lanes 0-7
      if (lane < 8){
        float* p = &pbuf[wvi][lane * 20];
        *(float4*)(p + 0)  = make_float4(c[0],  c[1],  c[2],  c[3]);
        *(float4*)(p + 4)  = make_float4(c[4],  c[5],  c[6],  c[7]);
        *(float4*)(p + 8)  = make_float4(c[8],  c[9],  c[10], c[11]);
        *(float4*)(p + 12) = make_float4(c[12], c[13], c[14], c[15]);
      }
      __syncthreads();
      {
        float s = pbuf[wq0 + part][cidx] + pbuf[wq0 + part + PL][cidx];
        s = addq2(addq1(s));
        if (PL == 8) s = addrhm(s);    // ^4 after quad-uniform
        if (part == 0) out[(size_t)seg * 128 + col] = 128.f * s;
      }
    } else {
      const float emu = emu_use[it];
      float c[16];
#pragma unroll
      for (int p = 0; p < 8; ++p){
        f32x2 e2 = ES2[p] * Et2;
        c[p*2+0] = e2[0]; c[p*2+1] = e2[1];
      }
#pragma unroll
      for (int k = 0; k < 16; ++k)
        c[k] = addx8(addx16(addx32(c[k])));        // valid lanes 0-7
      if (lane < 8){
        float* p = &pbuf[wvi][lane * 20];
        *(float4*)(p + 0)  = make_float4(c[0],  c[1],  c[2],  c[3]);
        *(float4*)(p + 4)  = make_float4(c[4],  c[5],  c[6],  c[7]);
        *(float4*)(p + 8)  = make_float4(c[8],  c[9],  c[10], c[11]);
        *(float4*)(p + 12) = make_float4(c[12], c[13], c[14], c[15]);
      }
      __syncthreads();                             // B1
      {
        float s = pbuf[wq0 + part][cidx] + pbuf[wq0 + part + PL][cidx];
        s = addq2(addq1(s));
        if (PL == 8) s = addrhm(s);
        if (part == 0) rcsb[hh][col] = emu * frcp(fmaxf(s, 1e-30f));   // Emu folded in
      }
      __syncthreads();                             // B2
      f32x2 rc2[8];
      {
        const float4 r0 = *(const float4*)&rcsb[hh][j * 16 + 0];
        const float4 r1 = *(const float4*)&rcsb[hh][j * 16 + 4];
        const float4 r2 = *(const float4*)&rcsb[hh][j * 16 + 8];
        const float4 r3 = *(const float4*)&rcsb[hh][j * 16 + 12];
        rc2[0] = (f32x2){r0.x, r0.y}; rc2[1] = (f32x2){r0.z, r0.w};
        rc2[2] = (f32x2){r1.x, r1.y}; rc2[3] = (f32x2){r1.z, r1.w};
        rc2[4] = (f32x2){r2.x, r2.y}; rc2[5] = (f32x2){r2.z, r2.w};
        rc2[6] = (f32x2){r3.x, r3.y}; rc2[7] = (f32x2){r3.z, r3.w};
      }
#pragma unroll
      for (int p = 0; p < 8; ++p){
        f32x2 e2  = ES2[p] * Et2;
        f32x2 sn  = e2 * rc2[p];
        f32x2 arg = e2 * (rc2[p] - PZ2[p]);
        PZ2[p] *= (f32x2){__expf(arg[0]), __expf(arg[1])};
        S2[p] = sn;
      }
    }
  }
}

extern "C" void kernel_launch(void* const* d_in, const int* in_sizes, int n_in,
                              void* d_out, int out_size, void* d_ws, size_t ws_size,
                              hipStream_t stream){
  const float* x    = (const float*)d_in[0];
  const int*   batch= (const int*)  d_in[1];
  const float* W1   = (const float*)d_in[2];
  const float* W2   = (const float*)d_in[3];
  const float* a1r  = (const float*)d_in[4];
  const float* a2r  = (const float*)d_in[5];
  const float* a3r  = (const float*)d_in[6];
  float* out = (float*)d_out;

  const int T  = in_sizes[1];        // rows of x
  const int Bn = out_size / 128;     // segments

  short* wpack  = (short*)d_ws;                       // 32768 bf16
  int*   starts = (int*)(wpack + 32768);              // Bn+1 ints
  int*   cnt    = starts + (Bn + 2);                  // 2 ints
  int*   bigs   = cnt + 2;                            // Bn ints
  int*   smalls = bigs + Bn;                          // Bn ints

  k_prep<<<17, 256, 0, stream>>>(W1, wpack, batch, starts, T, Bn,
                                 cnt, bigs, smalls);
  k_uot<<<Bn, 1024, 0, stream>>>(x, starts, cnt, bigs, smalls, wpack, W2,
                                 a1r, a2r, a3r, out, T);
}

// Round 17
// 80.699 us; speedup vs baseline: 1.1371x; 1.1371x over previous
//
#include <hip/hip_runtime.h>
#include <hip/hip_bf16.h>
#include <math.h>

#define NEGC -1000000000.0f

using f32x2 = __attribute__((ext_vector_type(2))) float;
using f32x4 = __attribute__((ext_vector_type(4))) float;
using s16x8 = __attribute__((ext_vector_type(8))) short;

__device__ __forceinline__ float softplusf(float v){ return log1pf(expf(v)); }
__device__ __forceinline__ float frcp(float v){ return __builtin_amdgcn_rcpf(v); }
__device__ __forceinline__ short bfs(float f){      // compiler emits v_cvt_pk_bf16_f32 pairs
  __hip_bfloat16 h = __float2bfloat16(f);
  short s; __builtin_memcpy(&s, &h, 2); return s;
}

// ---- cross-lane adds fully OFF the DS pipe (VALU permlane/DPP); semantics HW-verified r9/r13 ----
__device__ __forceinline__ float addx32(float v){   // valid lanes 0-31
#if __has_builtin(__builtin_amdgcn_permlane32_swap)
  auto r = __builtin_amdgcn_permlane32_swap(__float_as_uint(v), __float_as_uint(v), false, false);
  return v + __uint_as_float(r[1]);
#else
  return v + __shfl_xor(v, 32, 64);
#endif
}
__device__ __forceinline__ float addx16(float v){   // valid lanes 0-15
#if __has_builtin(__builtin_amdgcn_permlane16_swap)
  auto r = __builtin_amdgcn_permlane16_swap(__float_as_uint(v), __float_as_uint(v), false, false);
  return v + __uint_as_float(r[1]);
#else
  return v + __shfl_xor(v, 16, 64);
#endif
}
__device__ __forceinline__ float addx8(float v){    // xor8 via DPP row_ror:8
  int s = __builtin_amdgcn_update_dpp(0, __float_as_int(v), 0x128, 0xF, 0xF, true);
  return v + __int_as_float(s);
}
__device__ __forceinline__ float addq1(float v){    // xor1 via quad_perm
  int s = __builtin_amdgcn_update_dpp(0, __float_as_int(v), 0xB1, 0xF, 0xF, true);
  return v + __int_as_float(s);
}
__device__ __forceinline__ float addq2(float v){    // xor2 via quad_perm
  int s = __builtin_amdgcn_update_dpp(0, __float_as_int(v), 0x4E, 0xF, 0xF, true);
  return v + __int_as_float(s);
}
// ^7 ROW_HALF_MIRROR: equals ^4-add when input is quad-uniform (after addq1+addq2)
__device__ __forceinline__ float addrhm(float v){
  int s = __builtin_amdgcn_update_dpp(0, __float_as_int(v), 0x141, 0xF, 0xF, true);
  return v + __int_as_float(s);
}
// ^15 ROW_MIRROR: equals ^8-add when input is 8-group-uniform
__device__ __forceinline__ float addrm(float v){
  int s = __builtin_amdgcn_update_dpp(0, __float_as_int(v), 0x140, 0xF, 0xF, true);
  return v + __int_as_float(s);
}

// ---------------- Kernel A: fused W1-pack + parallel segment classification (r15 version) -------
__global__ __launch_bounds__(256) void k_prep(const float* __restrict__ W1,
                                              short* __restrict__ wpack,
                                              const int* __restrict__ batch,
                                              int* __restrict__ starts, int T, int Bn,
                                              int* __restrict__ cnt,
                                              int* __restrict__ bigs,
                                              int* __restrict__ smalls){
  const int bx  = blockIdx.x;
  const int tid = threadIdx.x;
  if (bx < 16){
    int gid  = bx * 256 + tid;                 // 0..4095
    int lane = gid & 63;
    int ft   = gid >> 6;
    int kt   = ft >> 2;
    int dt   = ft & 3;
    const float* src = W1 + (size_t)(kt * 16 + (lane & 15)) * 128 + dt * 32 + (lane >> 4) * 8;
    short o[8];
#pragma unroll
    for (int e = 0; e < 8; ++e) o[e] = bfs(src[e]);
    *(s16x8*)(wpack + (size_t)gid * 8) = *(const s16x8*)o;
  } else {
    int t = (bx - 16) * 256 + tid;
    if (t > Bn) return;
    int lo = 0, hi = T;
    while (lo < hi){ int mid = (lo + hi) >> 1; if (batch[mid] < t) lo = mid + 1; else hi = mid; }
    if (t == Bn){ starts[Bn] = T; return; }
    starts[t] = lo;
    int lo2 = lo, hi2 = T;
    while (lo2 < hi2){ int mid = (lo2 + hi2) >> 1; if (batch[mid] <= t) lo2 = mid + 1; else hi2 = mid; }
    int nb = lo2 - lo;
    if (nb > 64) bigs[atomicAdd(&cnt[0], 1)] = t;
    else         smalls[atomicAdd(&cnt[1], 1)] = t;
  }
}

// ---------------- Kernel B: fused scores-MFMA + softmax + UOT-badmm (one item/block) ----------------
__global__ __launch_bounds__(1024)
void k_uot(const float* __restrict__ x,
           const int*   __restrict__ starts,
           const int*   __restrict__ cnt,
           const int*   __restrict__ bigs,
           const int*   __restrict__ smalls,
           const short* __restrict__ wpack,
           const float* __restrict__ W2,
           const float* __restrict__ a1r,
           const float* __restrict__ a2r,
           const float* __restrict__ a3r,
           float* __restrict__ out, int T){
  __shared__ __align__(16) short xs[2 * 64 * 128];      // 32 KB
  __shared__ __align__(16) float pbuf[16][164];
  __shared__ float scpart[2][4][64];
  __shared__ float rcsb[2][128];
  __shared__ float lq0s[2][128];
  __shared__ float sred[2][2];

  const int b   = blockIdx.x;
  const int tid = threadIdx.x;
  const int nbig   = cnt[0];
  const int nsmall = cnt[1];

  bool solo; int seg;
  const int half  = tid >> 9;
  const int tid_l = tid & 511;
  if (b < nbig){
    solo = true; seg = bigs[b];
  } else {
    const int i = (b - nbig) * 2 + half;
    solo = false;
    if ((b - nbig) * 2 >= nsmall) return;          // ghost block (uniform) -> no barrier reached
    if (i >= nsmall) return;                       // half B missing -> waves exit
    seg = smalls[i];
  }

  const int start = starts[seg];
  const int nbr   = starts[seg + 1] - start;
  const int hh    = solo ? 0 : half;
  const int tl    = solo ? tid : tid_l;
  const int PL    = solo ? 8 : 4;

  if (nbr <= 0){
    if (tl < 128) out[(size_t)seg * 128 + tl] = 0.f;
    return;
  }

  const int n    = tl >> 3;
  const int j    = tl & 7;
  const int wvi  = tid >> 6;
  const int lane = tid & 63;
  const int part = tl & (PL - 1);
  const int col  = tl / PL;
  const int cidx = (col >> 4) * 20 + (col & 15);
  const int wq0  = solo ? 0 : half * 8;

  // ===== Phase 1: stage unit rows as swizzled bf16 =====
  const int u      = tid >> 9;
  const int ustart = solo ? (start + u * 64) : start;
#pragma unroll
  for (int itr = 0; itr < 2; ++itr){
    int L  = (itr * 512 + tid_l) * 8;
    int rr = L >> 7;
    int dc = L & 127;
    int grow = ustart + rr; grow = (grow < T) ? grow : (T - 1);
    const float4 v0 = *(const float4*)(x + (size_t)grow * 128 + dc);
    const float4 v1 = *(const float4*)(x + (size_t)grow * 128 + dc + 4);
    short o[8] = {bfs(v0.x), bfs(v0.y), bfs(v0.z), bfs(v0.w),
                  bfs(v1.x), bfs(v1.y), bfs(v1.z), bfs(v1.w)};
    int byte = u * 16384 + rr * 256 + ((dc * 2) ^ ((rr & 7) << 4));
    *(s16x8*)((char*)xs + byte) = *(const s16x8*)o;
  }
  __syncthreads();

  // ===== Phase 2: scores MFMA + tanh*W2 epilogue =====
  {
    const int lw = wvi & 7;
    const int wm = lw & 1;
    const int wn = lw >> 1;
    f32x4 acc[2][4];
#pragma unroll
    for (int mt = 0; mt < 2; ++mt)
#pragma unroll
      for (int kt = 0; kt < 4; ++kt) acc[mt][kt] = (f32x4){0.f, 0.f, 0.f, 0.f};

    const s16x8* wp = (const s16x8*)wpack;
#pragma unroll
    for (int dt = 0; dt < 4; ++dt){
      s16x8 av[2];
#pragma unroll
      for (int mt = 0; mt < 2; ++mt){
        int arow = wm * 32 + mt * 16 + (lane & 15);
        int byte = u * 16384 + arow * 256 + ((dt * 64 + (lane >> 4) * 16) ^ ((arow & 7) << 4));
        av[mt] = *(const s16x8*)((const char*)xs + byte);
      }
#pragma unroll
      for (int kt = 0; kt < 4; ++kt){
        s16x8 wv = wp[(size_t)((((wn * 4 + kt) * 4 + dt)) << 6) + lane];
#pragma unroll
        for (int mt = 0; mt < 2; ++mt)
          acc[mt][kt] = __builtin_amdgcn_mfma_f32_16x16x32_bf16(av[mt], wv, acc[mt][kt], 0, 0, 0);
      }
    }

    float psum[2][4] = {{0.f,0.f,0.f,0.f},{0.f,0.f,0.f,0.f}};
#pragma unroll
    for (int kt = 0; kt < 4; ++kt){
      const float w2v  = W2[(wn * 4 + kt) * 16 + (lane & 15)];
      const float w2v2 = w2v + w2v;
#pragma unroll
      for (int mt = 0; mt < 2; ++mt)
#pragma unroll
        for (int r = 0; r < 4; ++r){
          float e = __expf(2.f * acc[mt][kt][r]);
          psum[mt][r] = fmaf(-w2v2, frcp(e + 1.f), psum[mt][r] + w2v);   // += tanh*w2
        }
    }
#pragma unroll
    for (int mt = 0; mt < 2; ++mt)
#pragma unroll
      for (int r = 0; r < 4; ++r){
        float v = psum[mt][r];
        v = addq1(v); v = addq2(v);
        v = addrhm(v);                 // ^4 (quad-uniform)
        v = addrm(v);                  // ^8 (8-uniform)
        if ((lane & 15) == 0)
          scpart[u][wn][wm * 32 + mt * 16 + (lane >> 4) * 4 + r] = v;
      }
  }
  __syncthreads();

  // ===== Phase 3': merged score-combine + softmax stats (one barrier) =====
  float sc = NEGC;
  if (tl < 128 && tl < nbr){
    const int ru = solo ? (tl >> 6) : hh;
    const int rl = tl & 63;
    sc = scpart[ru][0][rl] + scpart[ru][1][rl] + scpart[ru][2][rl] + scpart[ru][3][rl];
  }
  if (tl < 128) lq0s[hh][tl] = sc;
  if ((wvi & 7) == 0 && (!solo || wvi == 0)){
    float v1 = NEGC;
    const int r2 = lane + 64;
    if (r2 < nbr){                               // only possible for solo
      const int rl2 = r2 & 63;
      v1 = scpart[1][0][rl2] + scpart[1][1][rl2] + scpart[1][2][rl2] + scpart[1][3][rl2];
    }
    float m = fmaxf(sc, v1);
#pragma unroll
    for (int msk = 32; msk; msk >>= 1) m = fmaxf(m, __shfl_xor(m, msk, 64));
    float s = __expf(sc - m) + __expf(v1 - m);
#pragma unroll
    for (int msk = 32; msk; msk >>= 1) s += __shfl_xor(s, msk, 64);
    if (lane == 0){ sred[hh][0] = m; sred[hh][1] = s; }
  }
  __syncthreads();
  const float smax  = sred[hh][0];
  const float rden  = frcp(sred[hh][1] + 1e-16f);
  const bool  valid = (n < nbr);
  const float lq0   = valid ? __logf(__expf(lq0s[hh][n] - smax) * rden + 1e-8f) : NEGC;

  // ===== Phase 4: scalars + per-row eta recursion =====
  const float a1 = softplusf(a1r[0]);
  const float a2 = softplusf(a2r[0]);
  const float a3 = softplusf(a3r[0]);
  const float inv_a1 = 1.f / a1;
  const float log_p0 = logf(1.0f / 128.0f + 1e-8f);

  float emu_use[3];
  {
    float z1 = 0.f, lp = log_p0;
    emu_use[0] = __expf(log_p0);
#pragma unroll
    for (int i = 1; i < 3; ++i){
      float nm = (a1 * lp + a2 * log_p0 - z1) / (a1 + a2);
      z1 += a1 * (__expf(nm) - __expf(lp));
      emu_use[i] = __expf(nm); lp = nm;
    }
  }
  float eeta_use[4];
  {
    float z2 = 0.f, lp = lq0;
    eeta_use[0] = __expf(lq0);
#pragma unroll
    for (int i = 1; i < 4; ++i){
      float nm = (a1 * lp + a3 * lq0 - z2) / (a1 + a3);
      z2 += a1 * (__expf(nm) - __expf(lp));
      eeta_use[i] = __expf(nm); lp = nm;
    }
  }

  const int  nc   = valid ? n : (nbr - 1);
  const float* xp = x + (size_t)(start + nc) * 128 + j * 16;    // always in-bounds
  f32x2 EX2[8], PZ2[8], S2[8];
  {
    const float s0 = __expf(lq0 + log_p0);       // exactly 0 for invalid rows
#pragma unroll
    for (int p = 0; p < 8; p += 2){
      float4 v = *(const float4*)(xp + p * 2);
      EX2[p]   = (f32x2){__expf(v.x * inv_a1), __expf(v.y * inv_a1)};
      EX2[p+1] = (f32x2){__expf(v.z * inv_a1), __expf(v.w * inv_a1)};
    }
#pragma unroll
    for (int p = 0; p < 8; ++p){ PZ2[p] = (f32x2){1.f, 1.f}; S2[p] = (f32x2){s0, s0}; }
  }

#pragma unroll
  for (int it = 0; it < 4; ++it){
    f32x2 ES2[8];
    f32x2 rs2 = (f32x2){0.f, 0.f};
#pragma unroll
    for (int p = 0; p < 8; ++p){
      ES2[p] = EX2[p] * S2[p];
      rs2 += ES2[p] * PZ2[p];
    }
    float rsum = rs2[0] + rs2[1];
    rsum = addq1(rsum);
    rsum = addq2(rsum);
    rsum = addrhm(rsum);               // ^4 (quad-uniform)
    const float Et = valid ? (eeta_use[it] * frcp(rsum)) : 0.f;
    const f32x2 Et2 = (f32x2){Et, Et};

    if (it == 3){
      float c[16];
#pragma unroll
      for (int p = 0; p < 8; p += 2){
        float4 v = *(const float4*)(xp + p * 2);
        f32x2 t0 = ES2[p]   * PZ2[p]   * Et2;
        f32x2 t1 = ES2[p+1] * PZ2[p+1] * Et2;
        c[p*2+0] = v.x * t0[0]; c[p*2+1] = v.y * t0[1];
        c[p*2+2] = v.z * t1[0]; c[p*2+3] = v.w * t1[1];
      }
#pragma unroll
      for (int k = 0; k < 16; ++k)
        c[k] = addx8(addx16(addx32(c[k])));        // valid lanes 0-7
      if (lane < 8){
        float* p = &pbuf[wvi][lane * 20];
        *(float4*)(p + 0)  = make_float4(c[0],  c[1],  c[2],  c[3]);
        *(float4*)(p + 4)  = make_float4(c[4],  c[5],  c[6],  c[7]);
        *(float4*)(p + 8)  = make_float4(c[8],  c[9],  c[10], c[11]);
        *(float4*)(p + 12) = make_float4(c[12], c[13], c[14], c[15]);
      }
      __syncthreads();
      {
        float s = pbuf[wq0 + part][cidx] + pbuf[wq0 + part + PL][cidx];
        s = addq2(addq1(s));
        if (PL == 8) s = addrhm(s);    // ^4 after quad-uniform
        if (part == 0) out[(size_t)seg * 128 + col] = 128.f * s;
      }
    } else {
      const float emu = emu_use[it];
      float c[16];
#pragma unroll
      for (int p = 0; p < 8; ++p){
        f32x2 e2 = ES2[p] * Et2;
        c[p*2+0] = e2[0]; c[p*2+1] = e2[1];
      }
#pragma unroll
      for (int k = 0; k < 16; ++k)
        c[k] = addx8(addx16(addx32(c[k])));        // valid lanes 0-7
      if (lane < 8){
        float* p = &pbuf[wvi][lane * 20];
        *(float4*)(p + 0)  = make_float4(c[0],  c[1],  c[2],  c[3]);
        *(float4*)(p + 4)  = make_float4(c[4],  c[5],  c[6],  c[7]);
        *(float4*)(p + 8)  = make_float4(c[8],  c[9],  c[10], c[11]);
        *(float4*)(p + 12) = make_float4(c[12], c[13], c[14], c[15]);
      }
      __syncthreads();                             // B1
      {
        float s = pbuf[wq0 + part][cidx] + pbuf[wq0 + part + PL][cidx];
        s = addq2(addq1(s));
        if (PL == 8) s = addrhm(s);
        if (part == 0) rcsb[hh][col] = emu * frcp(fmaxf(s, 1e-30f));   // Emu folded in
      }
      __syncthreads();                             // B2
      f32x2 rc2[8];
      {
        const float4 r0 = *(const float4*)&rcsb[hh][j * 16 + 0];
        const float4 r1 = *(const float4*)&rcsb[hh][j * 16 + 4];
        const float4 r2 = *(const float4*)&rcsb[hh][j * 16 + 8];
        const float4 r3 = *(const float4*)&rcsb[hh][j * 16 + 12];
        rc2[0] = (f32x2){r0.x, r0.y}; rc2[1] = (f32x2){r0.z, r0.w};
        rc2[2] = (f32x2){r1.x, r1.y}; rc2[3] = (f32x2){r1.z, r1.w};
        rc2[4] = (f32x2){r2.x, r2.y}; rc2[5] = (f32x2){r2.z, r2.w};
        rc2[6] = (f32x2){r3.x, r3.y}; rc2[7] = (f32x2){r3.z, r3.w};
      }
#pragma unroll
      for (int p = 0; p < 8; ++p){
        f32x2 e2  = ES2[p] * Et2;
        f32x2 sn  = e2 * rc2[p];
        f32x2 arg = e2 * (rc2[p] - PZ2[p]);
        PZ2[p] *= (f32x2){__expf(arg[0]), __expf(arg[1])};
        S2[p] = sn;
      }
    }
  }
}

extern "C" void kernel_launch(void* const* d_in, const int* in_sizes, int n_in,
                              void* d_out, int out_size, void* d_ws, size_t ws_size,
                              hipStream_t stream){
  const float* x    = (const float*)d_in[0];
  const int*   batch= (const int*)  d_in[1];
  const float* W1   = (const float*)d_in[2];
  const float* W2   = (const float*)d_in[3];
  const float* a1r  = (const float*)d_in[4];
  const float* a2r  = (const float*)d_in[5];
  const float* a3r  = (const float*)d_in[6];
  float* out = (float*)d_out;

  const int T  = in_sizes[1];        // rows of x
  const int Bn = out_size / 128;     // segments

  short* wpack  = (short*)d_ws;                       // 32768 bf16
  int*   starts = (int*)(wpack + 32768);              // Bn+1 ints
  int*   cnt    = starts + (Bn + 2);                  // 2 ints
  int*   bigs   = cnt + 2;                            // Bn ints
  int*   smalls = bigs + Bn;                          // Bn ints

  hipMemsetAsync(cnt, 0, 2 * sizeof(int), stream);
  const int segBlocks = (Bn + 256) / 256;
  k_prep<<<16 + segBlocks, 256, 0, stream>>>(W1, wpack, batch, starts, T, Bn,
                                             cnt, bigs, smalls);
  k_uot<<<Bn, 1024, 0, stream>>>(x, starts, cnt, bigs, smalls, wpack, W2,
                                 a1r, a2r, a3r, out, T);
}